// Round 10
// baseline (912.952 us; speedup 1.0000x reference)
//
#include <hip/hip_runtime.h>

#define ND 4
#define ED 128
#define KCODES 4096
#define NTOK 16384          // B*S
#define HID 512
#define NTOT (ND*ED*NTOK)   // 8388608

#define TM 128              // tokens per block
#define TN 128              // codes per k-tile
#define EB 16               // e-chunk staged per pass

// x2: STRICT SERIAL ascending-e, plain mul then add (XLA-CPU strict semantics)
__global__ __launch_bounds__(256) void x2_kernel(const float* __restrict__ in,
                                                 float* __restrict__ x2g) {
    int idx = blockIdx.x * 256 + threadIdx.x;    // 0..65535
    int t = idx >> 2, d = idx & 3;
    const float* __restrict__ p = in + (size_t)t * HID + d * ED;
    float s = 0.f;
    for (int e = 0; e < ED; ++e) {
        float v = p[e];
        s = __fadd_rn(s, __fmul_rn(v, v));
    }
    x2g[d * NTOK + t] = s;
}

// e2: strict serial ascending-e, plain mul then add
__global__ __launch_bounds__(256) void e2_kernel(const float* __restrict__ emb,
                                                 float* __restrict__ e2g) {
    int idx = blockIdx.x * 256 + threadIdx.x;     // 0..16383
    int d = idx >> 12;
    int k = idx & (KCODES - 1);
    const float* __restrict__ p = emb + (size_t)d * ED * KCODES + k;
    float s = 0.f;
    for (int e = 0; e < ED; ++e) {
        float v = p[(size_t)e * KCODES];
        s = __fadd_rn(s, __fmul_rn(v, v));
    }
    e2g[idx] = s;
}

// Fused cross-GEMM + argmin. cross = serial ascending-h FMA chain from 0
// (Eigen gebp / serial-k). dist = fsub(fadd(x2,e2), fmul(2,cross)).
// Grid: (NTOK/TM, ND). 256 threads = 16 kt x 16 ttk; 8x8 register tile.
__global__ __launch_bounds__(256) void argmin_kernel(const float* __restrict__ in,
        const float* __restrict__ emb, const float* __restrict__ x2g,
        const float* __restrict__ e2g, int* __restrict__ lat) {
    __shared__ float A[ED][TM];    // [e][t], 64 KB
    __shared__ float Bt[EB][TN];   // word-permuted rows, 8 KB
    __shared__ float E2[TN];
    __shared__ float X2s[TM];

    const int tid  = threadIdx.x;
    const int d    = blockIdx.y;
    const int t0   = blockIdx.x * TM;
    const float* __restrict__ embd = emb + (size_t)d * ED * KCODES;

    // Stage A transposed: A[e][t] = in[(t0+t)*512 + d*128 + e]
    {
        int trow = tid >> 5;             // 0..7
        int e4   = (tid & 31) << 2;      // 0,4,...,124
        #pragma unroll
        for (int i = 0; i < 16; ++i) {
            int t = trow + (i << 3);
            const float4 v = *(const float4*)(in + (size_t)(t0 + t) * HID + d * ED + e4);
            A[e4 + 0][t] = v.x;
            A[e4 + 1][t] = v.y;
            A[e4 + 2][t] = v.z;
            A[e4 + 3][t] = v.w;
        }
    }
    if (tid < TM) X2s[tid] = x2g[d * NTOK + t0 + tid];

    const int kt  = tid & 15;    // code-thread
    const int ttk = tid >> 4;    // token-thread

    float best[8];
    int   bestk[8];
    #pragma unroll
    for (int i = 0; i < 8; ++i) { best[i] = 3.0e38f; bestk[i] = 0; }

    for (int k0 = 0; k0 < KCODES; k0 += TN) {
        __syncthreads();                              // prev iter's E2/Bt readers done
        if (tid < TN) E2[tid] = e2g[d * KCODES + k0 + tid];

        float acc[8][8];
        #pragma unroll
        for (int a = 0; a < 8; ++a)
            #pragma unroll
            for (int b = 0; b < 8; ++b) acc[a][b] = 0.f;

        for (int e0 = 0; e0 < ED; e0 += EB) {
            __syncthreads();                          // prev chunk's Bt readers done
            {
                // stage Bt[e][perm(k)]; perm: p4 = ((k4&4)<<4) + ((k4>>3)<<2)
                int erow = tid >> 5;                  // 0..7
                int k4   = (tid & 31) << 2;           // logical k, 4-aligned
                int p4   = ((k4 & 4) << 4) + ((k4 >> 3) << 2);
                #pragma unroll
                for (int i = 0; i < 2; ++i) {
                    int ee = erow + (i << 3);
                    float4 v = *(const float4*)(embd + (size_t)(e0 + ee) * KCODES + k0 + k4);
                    *(float4*)&Bt[ee][p4] = v;
                }
            }
            __syncthreads();
            #pragma unroll 4
            for (int e = 0; e < EB; ++e) {
                float4 a0 = *(const float4*)&A[e0 + e][ttk * 8];
                float4 a1 = *(const float4*)&A[e0 + e][ttk * 8 + 4];
                float4 b0 = *(const float4*)&Bt[e][kt * 4];        // codes kt*8+0..3
                float4 b1 = *(const float4*)&Bt[e][64 + kt * 4];   // codes kt*8+4..7
                float av[8] = {a0.x, a0.y, a0.z, a0.w, a1.x, a1.y, a1.z, a1.w};
                float bv[8] = {b0.x, b0.y, b0.z, b0.w, b1.x, b1.y, b1.z, b1.w};
                #pragma unroll
                for (int a = 0; a < 8; ++a)
                    #pragma unroll
                    for (int b = 0; b < 8; ++b)
                        acc[a][b] = __fmaf_rn(av[a], bv[b], acc[a][b]);  // serial asc-h FMA
            }
        }
        // dist = (x2 + e2) - 2*cross, each op rounded once
        #pragma unroll
        for (int a = 0; a < 8; ++a) {
            float x2v = X2s[ttk * 8 + a];
            #pragma unroll
            for (int b = 0; b < 8; ++b) {
                float dist = __fsub_rn(__fadd_rn(x2v, E2[kt * 8 + b]),
                                       __fmul_rn(2.0f, acc[a][b]));
                int kidx = k0 + kt * 8 + b;
                if (dist < best[a]) { best[a] = dist; bestk[a] = kidx; }  // first min
            }
        }
    }

    // cross-thread merge (16 kt candidates per token), tie -> lowest k
    __syncthreads();
    float (*red_d)[16] = (float (*)[16])(&A[0][0]);
    int   (*red_k)[16] = (int   (*)[16])(&A[32][0]);
    #pragma unroll
    for (int a = 0; a < 8; ++a) {
        red_d[ttk * 8 + a][kt] = best[a];
        red_k[ttk * 8 + a][kt] = bestk[a];
    }
    __syncthreads();
    if (tid < TM) {
        float B1 = red_d[tid][0];
        int   K1 = red_k[tid][0];
        #pragma unroll
        for (int j = 1; j < 16; ++j) {
            float b1 = red_d[tid][j];
            int   kj = red_k[tid][j];
            if (b1 < B1 || (b1 == B1 && kj < K1)) { B1 = b1; K1 = kj; }
        }
        lat[d * NTOK + t0 + tid] = K1;
    }
}

// out[n] = fl(fl(x + e) - x), n = (d,e,t); per-block partials of (x - e)^2
__global__ __launch_bounds__(256) void gather_kernel(const float* __restrict__ in,
        const float* __restrict__ emb, const int* __restrict__ lat,
        float* __restrict__ out, float* __restrict__ partial) {
    int tid  = threadIdx.x;
    int base = blockIdx.x * 1024 + tid * 4;
    int d = base >> 21;
    int e = (base >> 14) & 127;
    int t = base & (NTOK - 1);
    const int4 kk = *(const int4*)(lat + d * NTOK + t);
    const float* __restrict__ row = emb + ((size_t)(d * ED + e)) * KCODES;
    float enc[4];
    enc[0] = row[kk.x]; enc[1] = row[kk.y]; enc[2] = row[kk.z]; enc[3] = row[kk.w];
    const float4 x = *(const float4*)(in + base);
    const float xv[4] = {x.x, x.y, x.z, x.w};
    float4 ov; float* o = (float*)&ov;
    float s = 0.f;
    #pragma unroll
    for (int i = 0; i < 4; ++i) {
        o[i] = __fsub_rn(__fadd_rn(xv[i], enc[i]), xv[i]);   // straight-through rounding
        float df = xv[i] - enc[i];
        s = __fmaf_rn(df, df, s);
    }
    *(float4*)(out + base) = ov;
    #pragma unroll
    for (int off = 32; off > 0; off >>= 1) s += __shfl_down(s, off, 64);
    __shared__ float wsum[4];
    if ((tid & 63) == 0) wsum[tid >> 6] = s;
    __syncthreads();
    if (tid == 0) partial[blockIdx.x] = wsum[0] + wsum[1] + wsum[2] + wsum[3];
}

__global__ __launch_bounds__(256) void finalize_kernel(const float* __restrict__ partial,
                                                       float* __restrict__ out_tail) {
    __shared__ double sh[256];
    double s = 0.0;
    for (int i = threadIdx.x; i < 8192; i += 256) s += (double)partial[i];
    sh[threadIdx.x] = s;
    __syncthreads();
    for (int w = 128; w > 0; w >>= 1) {
        if (threadIdx.x < w) sh[threadIdx.x] += sh[threadIdx.x + w];
        __syncthreads();
    }
    if (threadIdx.x == 0) {
        double mean = sh[0] / (double)NTOT;
        out_tail[0] = (float)(0.25 * mean);   // loss
        out_tail[1] = (float)mean;            // commit_loss
        ((int*)out_tail)[2] = 0;              // kl (int32 0 == fp32 0.0 bits)
    }
}

extern "C" void kernel_launch(void* const* d_in, const int* in_sizes, int n_in,
                              void* d_out, int out_size, void* d_ws, size_t ws_size,
                              hipStream_t stream) {
    const float* in  = (const float*)d_in[0];
    const float* emb = (const float*)d_in[1];
    float* out = (float*)d_out;

    int*   lat     = (int*)d_ws;                       // 65536 int
    float* x2g     = (float*)d_ws + 65536;             // 65536 f32
    float* e2g     = (float*)d_ws + 131072;            // 16384 f32
    float* partial = (float*)d_ws + 147456;            // 8192 f32

    hipLaunchKernelGGL(x2_kernel, dim3(256), dim3(256), 0, stream, in, x2g);
    hipLaunchKernelGGL(e2_kernel, dim3(64), dim3(256), 0, stream, emb, e2g);
    hipLaunchKernelGGL(argmin_kernel, dim3(NTOK / TM, ND), dim3(256), 0, stream,
                       in, emb, x2g, e2g, lat);
    hipLaunchKernelGGL(gather_kernel, dim3(NTOT / 1024), dim3(256), 0, stream,
                       in, emb, lat, out, partial);
    hipLaunchKernelGGL(finalize_kernel, dim3(1), dim3(256), 0, stream, partial, out + NTOT);
}

// Round 11
// 420.133 us; speedup vs baseline: 2.1730x; 2.1730x over previous
//
#include <hip/hip_runtime.h>

#define ND 4
#define ED 128
#define KCODES 4096
#define NTOK 16384          // B*S
#define HID 512
#define NTOT (ND*ED*NTOK)   // 8388608

#define MARGIN 2.0e-3f
#define FLAG_CAP 8192

typedef __attribute__((ext_vector_type(8))) short short8v;
typedef __attribute__((ext_vector_type(4))) float float4v;

__device__ __forceinline__ unsigned short bf16h(float x) {
    unsigned u = __float_as_uint(x);
    return (unsigned short)((u + 0x7fffu + ((u >> 16) & 1u)) >> 16);
}
__device__ __forceinline__ float bf16f(unsigned short h) {
    return __uint_as_float(((unsigned)h) << 16);
}

__global__ void zero_kernel(int* __restrict__ p) { if (threadIdx.x == 0) *p = 0; }

// x2: strict serial ascending-e, plain mul then add (bit-matches ref; repair-only input)
__global__ __launch_bounds__(256) void x2_kernel(const float* __restrict__ in,
                                                 float* __restrict__ x2g) {
    int idx = blockIdx.x * 256 + threadIdx.x;    // 0..65535
    int t = idx >> 2, d = idx & 3;
    const float* __restrict__ p = in + (size_t)t * HID + d * ED;
    float s = 0.f;
    for (int e = 0; e < ED; ++e) {
        float v = p[e];
        s = __fadd_rn(s, __fmul_rn(v, v));
    }
    x2g[d * NTOK + t] = s;
}

// e2: strict serial ascending-e, plain mul then add (bit-matches ref)
__global__ __launch_bounds__(256) void e2_kernel(const float* __restrict__ emb,
                                                 float* __restrict__ e2g) {
    int idx = blockIdx.x * 256 + threadIdx.x;     // 0..16383
    int d = idx >> 12;
    int k = idx & (KCODES - 1);
    const float* __restrict__ p = emb + (size_t)d * ED * KCODES + k;
    float s = 0.f;
    for (int e = 0; e < ED; ++e) {
        float v = p[(size_t)e * KCODES];
        s = __fadd_rn(s, __fmul_rn(v, v));
    }
    e2g[idx] = s;
}

// Pre-split + transpose B: emb[d][e][k] f32 -> bth/btl[d][k][e] bf16 (hi/lo Dekker split)
__global__ __launch_bounds__(256) void bsplit_kernel(const float* __restrict__ emb,
        unsigned short* __restrict__ bth, unsigned short* __restrict__ btl) {
    __shared__ float T[128][65];
    const int k0  = blockIdx.x * 64;
    const int d   = blockIdx.y;
    const int tid = threadIdx.x;
    for (int i = 0; i < 32; ++i) {
        int e = i * 4 + (tid >> 6);
        int k = tid & 63;
        T[e][k] = emb[((size_t)d * ED + e) * KCODES + k0 + k];
    }
    __syncthreads();
    int k  = tid >> 2;
    int eg = tid & 3;
    size_t base = ((size_t)(d * KCODES + k0 + k)) * ED;
    for (int c = 0; c < 4; ++c) {
        int e0 = eg * 32 + c * 8;
        short8v hv, lv;
        #pragma unroll
        for (int j = 0; j < 8; ++j) {
            float x = T[e0 + j][k];
            unsigned short hb = bf16h(x);
            hv[j] = (short)hb;
            lv[j] = (short)bf16h(x - bf16f(hb));
        }
        *(short8v*)(bth + base + e0) = hv;
        *(short8v*)(btl + base + e0) = lv;
    }
}

// MFMA bf16x3 fast argmin: dist_f = fma(-2, cross, e2). Tracks best/2nd-best,
// flags gap < MARGIN for exact repair. Grid (256, ND), 256 thr = 4 waves x 16 rows.
__global__ __launch_bounds__(256) void argmin_mfma_kernel(const float* __restrict__ in,
        const unsigned short* __restrict__ bth, const unsigned short* __restrict__ btl,
        const float* __restrict__ e2g, int* __restrict__ lat,
        int* __restrict__ flag_cnt, int* __restrict__ flag_list) {
    __shared__ unsigned short BhL[64 * 128];   // [code][e] XOR-swizzled, 16 KB
    __shared__ unsigned short BlL[64 * 128];   // 16 KB

    const int tid  = threadIdx.x;
    const int d    = blockIdx.y;
    const int t0   = blockIdx.x * 64;
    const int wid  = tid >> 6;      // wave = row-tile (16 tokens)
    const int lane = tid & 63;
    const int lrow = lane & 15;
    const int lk8  = lane >> 4;     // 0..3

    // A fragments (f32 -> bf16 hi/lo) straight from global; row = t0+wid*16+lrow,
    // k(=e) = ks*32 + lk8*8 + j  (16x16x32 A layout: lane=row + 16*(k/8))
    short8v ahf[4], alf[4];
    {
        const float* ap = in + (size_t)(t0 + wid * 16 + lrow) * HID + d * ED + lk8 * 8;
        #pragma unroll
        for (int ks = 0; ks < 4; ++ks) {
            float4 v0 = *(const float4*)(ap + ks * 32);
            float4 v1 = *(const float4*)(ap + ks * 32 + 4);
            float vv[8] = {v0.x, v0.y, v0.z, v0.w, v1.x, v1.y, v1.z, v1.w};
            short8v h, l;
            #pragma unroll
            for (int j = 0; j < 8; ++j) {
                unsigned short hb = bf16h(vv[j]);
                h[j] = (short)hb;
                l[j] = (short)bf16h(vv[j] - bf16f(hb));
            }
            ahf[ks] = h; alf[ks] = l;
        }
    }

    float best[4], best2[4];
    int   bestk[4];
    #pragma unroll
    for (int r = 0; r < 4; ++r) { best[r] = 3.0e38f; best2[r] = 3.0e38f; bestk[r] = 0; }

    // staging mapping: thread -> (code row, 32-e chunk)
    const int scode = tid >> 2;
    const int seb   = (tid & 3) * 32;
    const unsigned short* gh = bth + ((size_t)(d * KCODES) + scode) * ED + seb;
    const unsigned short* gl = btl + ((size_t)(d * KCODES) + scode) * ED + seb;
    char* bhB = (char*)BhL;
    char* blB = (char*)BlL;
    const int swrow = scode * 256;
    const int sxor  = (scode & 7) << 4;

    for (int tile = 0; tile < 64; ++tile) {
        const int tn0 = tile * 64;
        __syncthreads();                         // prev tile's frag readers done
        #pragma unroll
        for (int c = 0; c < 4; ++c) {
            int bir = (seb + c * 8) * 2;
            *(short8v*)(bhB + swrow + (bir ^ sxor)) =
                *(const short8v*)(gh + (size_t)tn0 * ED + c * 8);
            *(short8v*)(blB + swrow + (bir ^ sxor)) =
                *(const short8v*)(gl + (size_t)tn0 * ED + c * 8);
        }
        __syncthreads();
        for (int ct = 0; ct < 4; ++ct) {
            const int colLocal = ct * 16 + lrow;
            const int rbase = colLocal * 256;
            const int rxor  = (colLocal & 7) << 4;
            short8v bh[4], bl[4];
            #pragma unroll
            for (int ks = 0; ks < 4; ++ks) {
                int bir = ks * 64 + lk8 * 16;
                bh[ks] = *(const short8v*)(bhB + rbase + (bir ^ rxor));
                bl[ks] = *(const short8v*)(blB + rbase + (bir ^ rxor));
            }
            float4v acc = {0.f, 0.f, 0.f, 0.f};
            #pragma unroll
            for (int ks = 0; ks < 4; ++ks) {
                acc = __builtin_amdgcn_mfma_f32_16x16x32_bf16(ahf[ks], bh[ks], acc, 0, 0, 0);
                acc = __builtin_amdgcn_mfma_f32_16x16x32_bf16(alf[ks], bh[ks], acc, 0, 0, 0);
                acc = __builtin_amdgcn_mfma_f32_16x16x32_bf16(ahf[ks], bl[ks], acc, 0, 0, 0);
            }
            const int code  = tn0 + colLocal;
            const float e2v = e2g[d * KCODES + code];
            #pragma unroll
            for (int r = 0; r < 4; ++r) {      // C layout: col=lane&15, row=(lane>>4)*4+r
                float distv = __fmaf_rn(-2.0f, acc[r], e2v);
                if (distv < best[r]) { best2[r] = best[r]; best[r] = distv; bestk[r] = code; }
                else if (distv < best2[r]) { best2[r] = distv; }
            }
        }
    }

    // merge the 16 column-lanes (butterfly), tie -> lowest k
    #pragma unroll
    for (int m = 1; m <= 8; m <<= 1) {
        #pragma unroll
        for (int r = 0; r < 4; ++r) {
            float od = __shfl_xor(best[r], m, 64);
            float o2 = __shfl_xor(best2[r], m, 64);
            int   ok = __shfl_xor(bestk[r], m, 64);
            if (od < best[r] || (od == best[r] && ok < bestk[r])) {
                best2[r] = fminf(best[r], o2);
                best[r]  = od;
                bestk[r] = ok;
            } else {
                best2[r] = fminf(best2[r], od);
            }
        }
    }
    if (lrow == 0) {
        #pragma unroll
        for (int r = 0; r < 4; ++r) {
            int row = wid * 16 + lk8 * 4 + r;
            int tok = d * NTOK + t0 + row;
            lat[tok] = bestk[r];
            if (best2[r] - best[r] < MARGIN) {
                int slot = atomicAdd(flag_cnt, 1);
                if (slot < FLAG_CAP) flag_list[slot] = tok;
            }
        }
    }
}

// Exact repair, bit-matching the verified ref semantics: cross = serial ascending-e
// f32 FMA; dist = fsub(fadd(x2,e2), fmul(2,cross)); first-min over ascending k.
__global__ __launch_bounds__(256) void repair_kernel(const float* __restrict__ in,
        const float* __restrict__ emb, const float* __restrict__ x2g,
        const float* __restrict__ e2g, const int* __restrict__ flag_cnt,
        const int* __restrict__ flag_list, int* __restrict__ lat) {
    __shared__ float xs[ED];
    __shared__ float rd[256];
    __shared__ int   rk[256];
    int n = *flag_cnt;
    if (n > FLAG_CAP) n = FLAG_CAP;
    for (int idx = blockIdx.x; idx < n; idx += gridDim.x) {
        int tok = flag_list[idx];
        int d = tok >> 14;               // tok = d*NTOK + t
        int t = tok & (NTOK - 1);
        __syncthreads();
        if (threadIdx.x < ED) xs[threadIdx.x] = in[(size_t)t * HID + d * ED + threadIdx.x];
        __syncthreads();
        const float x2v = x2g[tok];
        const float* __restrict__ embd = emb + (size_t)d * ED * KCODES;
        float bd = 3.0e38f; int bk = 0;
        for (int j = 0; j < 16; ++j) {
            int k = threadIdx.x + j * 256;      // ascending k per thread
            float acc = 0.f;
            #pragma unroll 16
            for (int e = 0; e < ED; ++e)
                acc = __fmaf_rn(xs[e], embd[(size_t)e * KCODES + k], acc);
            float dist = __fsub_rn(__fadd_rn(x2v, e2g[d * KCODES + k]),
                                   __fmul_rn(2.0f, acc));
            if (dist < bd) { bd = dist; bk = k; }
        }
        rd[threadIdx.x] = bd; rk[threadIdx.x] = bk;
        __syncthreads();
        for (int w = 128; w > 0; w >>= 1) {
            if (threadIdx.x < w) {
                float od = rd[threadIdx.x + w]; int ok = rk[threadIdx.x + w];
                if (od < rd[threadIdx.x] || (od == rd[threadIdx.x] && ok < rk[threadIdx.x])) {
                    rd[threadIdx.x] = od; rk[threadIdx.x] = ok;
                }
            }
            __syncthreads();
        }
        if (threadIdx.x == 0) lat[tok] = rk[0];
    }
}

// out[n] = fl(fl(x + e) - x), n = (d,e,t); per-block partials of (x - e)^2
__global__ __launch_bounds__(256) void gather_kernel(const float* __restrict__ in,
        const float* __restrict__ emb, const int* __restrict__ lat,
        float* __restrict__ out, float* __restrict__ partial) {
    int tid  = threadIdx.x;
    int base = blockIdx.x * 1024 + tid * 4;
    int d = base >> 21;
    int e = (base >> 14) & 127;
    int t = base & (NTOK - 1);
    const int4 kk = *(const int4*)(lat + d * NTOK + t);
    const float* __restrict__ row = emb + ((size_t)(d * ED + e)) * KCODES;
    float enc[4];
    enc[0] = row[kk.x]; enc[1] = row[kk.y]; enc[2] = row[kk.z]; enc[3] = row[kk.w];
    const float4 x = *(const float4*)(in + base);
    const float xv[4] = {x.x, x.y, x.z, x.w};
    float4 ov; float* o = (float*)&ov;
    float s = 0.f;
    #pragma unroll
    for (int i = 0; i < 4; ++i) {
        o[i] = __fsub_rn(__fadd_rn(xv[i], enc[i]), xv[i]);
        float df = xv[i] - enc[i];
        s = __fmaf_rn(df, df, s);
    }
    *(float4*)(out + base) = ov;
    #pragma unroll
    for (int off = 32; off > 0; off >>= 1) s += __shfl_down(s, off, 64);
    __shared__ float wsum[4];
    if ((tid & 63) == 0) wsum[tid >> 6] = s;
    __syncthreads();
    if (tid == 0) partial[blockIdx.x] = wsum[0] + wsum[1] + wsum[2] + wsum[3];
}

__global__ __launch_bounds__(256) void finalize_kernel(const float* __restrict__ partial,
                                                       float* __restrict__ out_tail) {
    __shared__ double sh[256];
    double s = 0.0;
    for (int i = threadIdx.x; i < 8192; i += 256) s += (double)partial[i];
    sh[threadIdx.x] = s;
    __syncthreads();
    for (int w = 128; w > 0; w >>= 1) {
        if (threadIdx.x < w) sh[threadIdx.x] += sh[threadIdx.x + w];
        __syncthreads();
    }
    if (threadIdx.x == 0) {
        double mean = sh[0] / (double)NTOT;
        out_tail[0] = (float)(0.25 * mean);   // loss
        out_tail[1] = (float)mean;            // commit_loss
        ((int*)out_tail)[2] = 0;              // kl (int32 0 == fp32 0.0 bits)
    }
}

extern "C" void kernel_launch(void* const* d_in, const int* in_sizes, int n_in,
                              void* d_out, int out_size, void* d_ws, size_t ws_size,
                              hipStream_t stream) {
    const float* in  = (const float*)d_in[0];
    const float* emb = (const float*)d_in[1];
    float* out = (float*)d_out;
    char* ws = (char*)d_ws;

    int*   lat       = (int*)ws;                         // 256 KB
    float* x2g       = (float*)(ws + 262144);            // 256 KB
    float* e2g       = (float*)(ws + 524288);            // 64 KB
    float* partial   = (float*)(ws + 589824);            // 32 KB
    int*   flag_cnt  = (int*)(ws + 622592);              // 4 B
    int*   flag_list = (int*)(ws + 622596);              // 32 KB
    unsigned short* bth = (unsigned short*)(ws + (1 << 20));             // 4 MB
    unsigned short* btl = (unsigned short*)(ws + (1 << 20) + 4194304);   // 4 MB

    hipLaunchKernelGGL(zero_kernel, dim3(1), dim3(64), 0, stream, flag_cnt);
    hipLaunchKernelGGL(x2_kernel, dim3(256), dim3(256), 0, stream, in, x2g);
    hipLaunchKernelGGL(e2_kernel, dim3(64), dim3(256), 0, stream, emb, e2g);
    hipLaunchKernelGGL(bsplit_kernel, dim3(64, 4), dim3(256), 0, stream, emb, bth, btl);
    hipLaunchKernelGGL(argmin_mfma_kernel, dim3(256, 4), dim3(256), 0, stream,
                       in, bth, btl, e2g, lat, flag_cnt, flag_list);
    hipLaunchKernelGGL(repair_kernel, dim3(64), dim3(256), 0, stream,
                       in, emb, x2g, e2g, flag_cnt, flag_list, lat);
    hipLaunchKernelGGL(gather_kernel, dim3(NTOT / 1024), dim3(256), 0, stream,
                       in, emb, lat, out, partial);
    hipLaunchKernelGGL(finalize_kernel, dim3(1), dim3(256), 0, stream, partial, out + NTOT);
}

// Round 12
// 313.209 us; speedup vs baseline: 2.9148x; 1.3414x over previous
//
#include <hip/hip_runtime.h>

#define ND 4
#define ED 128
#define KCODES 4096
#define NTOK 16384          // B*S
#define HID 512
#define NTOT (ND*ED*NTOK)   // 8388608

#define MARGIN 2.0e-3f
#define FLAG_CAP 16384

typedef __attribute__((ext_vector_type(8))) short short8v;
typedef __attribute__((ext_vector_type(4))) float float4v;

__device__ __forceinline__ unsigned short bf16h(float x) {
    unsigned u = __float_as_uint(x);
    return (unsigned short)((u + 0x7fffu + ((u >> 16) & 1u)) >> 16);
}
__device__ __forceinline__ float bf16f(unsigned short h) {
    return __uint_as_float(((unsigned)h) << 16);
}

__global__ void zero_kernel(int* __restrict__ p) { if (threadIdx.x == 0) *p = 0; }

// e2 exact (serial asc-e mul/add, bit-matches ref) + biased copy e2p = e2 + 512
__global__ __launch_bounds__(256) void e2_kernel(const float* __restrict__ emb,
        float* __restrict__ e2g, float* __restrict__ e2p) {
    int idx = blockIdx.x * 256 + threadIdx.x;     // 0..16383
    int d = idx >> 12;
    int k = idx & (KCODES - 1);
    const float* __restrict__ p = emb + (size_t)d * ED * KCODES + k;
    float s = 0.f;
    for (int e = 0; e < ED; ++e) {
        float v = p[(size_t)e * KCODES];
        s = __fadd_rn(s, __fmul_rn(v, v));
    }
    e2g[idx] = s;
    e2p[idx] = s + 512.0f;
}

// B pre-split into MFMA-fragment order: bth2/btl2[d][tile64][blk=ks*4+kh][code][8e]
// (chunk c in [0,1024) per tile: code=c&63, blk=c>>6, e0=(blk>>2)*32+(blk&3)*8)
__global__ __launch_bounds__(256) void bsplit_kernel(const float* __restrict__ emb,
        unsigned short* __restrict__ bth2, unsigned short* __restrict__ btl2) {
    const int tile = blockIdx.x;    // 0..63 (64 codes each)
    const int d    = blockIdx.y;
    const int tid  = threadIdx.x;
    #pragma unroll
    for (int q = 0; q < 4; ++q) {
        int c    = q * 256 + tid;          // 0..1023
        int code = c & 63;
        int blk  = c >> 6;                 // 0..15
        int e0   = (blk >> 2) * 32 + (blk & 3) * 8;
        short8v hv, lv;
        #pragma unroll
        for (int j = 0; j < 8; ++j) {
            float v = emb[((size_t)d * ED + e0 + j) * KCODES + tile * 64 + code];
            unsigned short hb = bf16h(v);
            hv[j] = (short)hb;
            lv[j] = (short)bf16h(v - bf16f(hb));
        }
        size_t dst = ((size_t)(d * 64 + tile) * 1024 + c) * 8;
        *(short8v*)(bth2 + dst) = hv;
        *(short8v*)(btl2 + dst) = lv;
    }
}

// MFMA bf16x3 argmin, 2 row-tiles/wave (32 tok), linear-staged LDS B tiles.
// dist_fast = fma(-2, cross, e2+512). best/2nd-best + near-tie flags -> exact repair.
__global__ __launch_bounds__(256, 2) void argmin_mfma_kernel(const float* __restrict__ in,
        const unsigned short* __restrict__ bth2, const unsigned short* __restrict__ btl2,
        const float* __restrict__ e2p, int* __restrict__ lat,
        int* __restrict__ flag_cnt, int* __restrict__ flag_list) {
    __shared__ __align__(16) unsigned short Bst[16384];   // 32 KB: 2048 chunks x 16B

    // XCD-aware decode: blocks on one XCD share one d (B panel stays L2-resident)
    const int l    = blockIdx.x;          // 0..511
    const int r8   = l & 7;
    const int d    = r8 >> 1;
    const int tI   = 2 * (l >> 3) + (r8 & 1);   // 0..127 token-tile
    const int t0   = tI * 128;

    const int tid  = threadIdx.x;
    const int wid  = tid >> 6;      // wave id: 32 tokens each
    const int lane = tid & 63;
    const int l15  = lane & 15;
    const int lk8  = lane >> 4;     // 0..3

    // A fragments: rows t0 + wid*32 + rt*16 + l15, e = ks*32 + lk8*8 + j
    short8v ahf[2][4], alf[2][4];
    #pragma unroll
    for (int rt = 0; rt < 2; ++rt) {
        const float* ap = in + (size_t)(t0 + wid * 32 + rt * 16 + l15) * HID + d * ED + lk8 * 8;
        #pragma unroll
        for (int ks = 0; ks < 4; ++ks) {
            float4 v0 = *(const float4*)(ap + ks * 32);
            float4 v1 = *(const float4*)(ap + ks * 32 + 4);
            float vv[8] = {v0.x, v0.y, v0.z, v0.w, v1.x, v1.y, v1.z, v1.w};
            short8v h, lo;
            #pragma unroll
            for (int j = 0; j < 8; ++j) {
                unsigned short hb = bf16h(vv[j]);
                h[j]  = (short)hb;
                lo[j] = (short)bf16h(vv[j] - bf16f(hb));
            }
            ahf[rt][ks] = h; alf[rt][ks] = lo;
        }
    }

    float best1[2][4], best2_[2][4];
    int   bestk_[2][4];
    #pragma unroll
    for (int rt = 0; rt < 2; ++rt)
        #pragma unroll
        for (int r = 0; r < 4; ++r) { best1[rt][r] = 3.0e38f; best2_[rt][r] = 3.0e38f; bestk_[rt][r] = 0; }

    // prefetch tile 0 staging chunks (linear): chunk c = j*256 + tid
    short8v st[8];
    {
        const size_t tb = (size_t)(d * 64 + 0) * 1024;
        #pragma unroll
        for (int j = 0; j < 4; ++j) st[j]     = *(const short8v*)(bth2 + (tb + j * 256 + tid) * 8);
        #pragma unroll
        for (int j = 0; j < 4; ++j) st[4 + j] = *(const short8v*)(btl2 + (tb + j * 256 + tid) * 8);
    }

    const int khoff = lk8 * 512;    // (kh)*64 chunks *8 ushorts

    for (int kt = 0; kt < 64; ++kt) {
        __syncthreads();                       // prev tile's readers done
        #pragma unroll
        for (int j = 0; j < 8; ++j)
            *(short8v*)(&Bst[(size_t)(j * 256 + tid) * 8]) = st[j];
        __syncthreads();                       // staged visible

        if (kt < 63) {
            const size_t tb = (size_t)(d * 64 + kt + 1) * 1024;
            #pragma unroll
            for (int j = 0; j < 4; ++j) st[j]     = *(const short8v*)(bth2 + (tb + j * 256 + tid) * 8);
            #pragma unroll
            for (int j = 0; j < 4; ++j) st[4 + j] = *(const short8v*)(btl2 + (tb + j * 256 + tid) * 8);
        }
        // prefetch biased e2 for this tile's 4 ct columns
        float e2p4[4];
        #pragma unroll
        for (int ct = 0; ct < 4; ++ct)
            e2p4[ct] = e2p[d * KCODES + kt * 64 + ct * 16 + l15];

        #pragma unroll
        for (int ct = 0; ct < 4; ++ct) {
            const int cbase = (ct * 16 + l15) * 8;
            short8v bh[4], bl[4];
            #pragma unroll
            for (int ks = 0; ks < 4; ++ks) {
                bh[ks] = *(const short8v*)&Bst[ks * 2048 + khoff + cbase];
                bl[ks] = *(const short8v*)&Bst[8192 + ks * 2048 + khoff + cbase];
            }
            float4v ach[2] = {{0,0,0,0},{0,0,0,0}};
            float4v acl1[2] = {{0,0,0,0},{0,0,0,0}};
            float4v acl2[2] = {{0,0,0,0},{0,0,0,0}};
            #pragma unroll
            for (int ks = 0; ks < 4; ++ks) {
                ach[0]  = __builtin_amdgcn_mfma_f32_16x16x32_bf16(ahf[0][ks], bh[ks], ach[0], 0, 0, 0);
                ach[1]  = __builtin_amdgcn_mfma_f32_16x16x32_bf16(ahf[1][ks], bh[ks], ach[1], 0, 0, 0);
                acl1[0] = __builtin_amdgcn_mfma_f32_16x16x32_bf16(alf[0][ks], bh[ks], acl1[0], 0, 0, 0);
                acl1[1] = __builtin_amdgcn_mfma_f32_16x16x32_bf16(alf[1][ks], bh[ks], acl1[1], 0, 0, 0);
                acl2[0] = __builtin_amdgcn_mfma_f32_16x16x32_bf16(ahf[0][ks], bl[ks], acl2[0], 0, 0, 0);
                acl2[1] = __builtin_amdgcn_mfma_f32_16x16x32_bf16(ahf[1][ks], bl[ks], acl2[1], 0, 0, 0);
            }
            const int codev = kt * 64 + ct * 16 + l15;
            #pragma unroll
            for (int rt = 0; rt < 2; ++rt) {
                #pragma unroll
                for (int r = 0; r < 4; ++r) {
                    float cs = ach[rt][r] + acl1[rt][r] + acl2[rt][r];
                    float dv = __fmaf_rn(-2.0f, cs, e2p4[ct]);
                    if (dv < best1[rt][r]) {
                        best2_[rt][r] = best1[rt][r]; best1[rt][r] = dv; bestk_[rt][r] = codev;
                    } else if (dv < best2_[rt][r]) {
                        best2_[rt][r] = dv;
                    }
                }
            }
        }
    }

    // merge the 16 column-lanes (butterfly), tie -> lowest k
    #pragma unroll
    for (int m = 1; m <= 8; m <<= 1) {
        #pragma unroll
        for (int rt = 0; rt < 2; ++rt) {
            #pragma unroll
            for (int r = 0; r < 4; ++r) {
                float od = __shfl_xor(best1[rt][r], m, 64);
                float o2 = __shfl_xor(best2_[rt][r], m, 64);
                int   ok = __shfl_xor(bestk_[rt][r], m, 64);
                if (od < best1[rt][r] || (od == best1[rt][r] && ok < bestk_[rt][r])) {
                    best2_[rt][r] = fminf(best1[rt][r], o2);
                    best1[rt][r]  = od;
                    bestk_[rt][r] = ok;
                } else {
                    best2_[rt][r] = fminf(best2_[rt][r], od);
                }
            }
        }
    }
    if (l15 == 0) {
        #pragma unroll
        for (int rt = 0; rt < 2; ++rt) {
            #pragma unroll
            for (int r = 0; r < 4; ++r) {
                int row = wid * 32 + rt * 16 + lk8 * 4 + r;
                int tok = d * NTOK + t0 + row;
                lat[tok] = bestk_[rt][r];
                if (best2_[rt][r] - best1[rt][r] < MARGIN) {
                    int slot = atomicAdd(flag_cnt, 1);
                    if (slot < FLAG_CAP) flag_list[slot] = tok;
                }
            }
        }
    }
}

// Exact repair, bit-matching verified ref semantics (x2 computed in-kernel).
__global__ __launch_bounds__(256) void repair_kernel(const float* __restrict__ in,
        const float* __restrict__ emb, const float* __restrict__ e2g,
        const int* __restrict__ flag_cnt, const int* __restrict__ flag_list,
        int* __restrict__ lat) {
    __shared__ float xs[ED];
    __shared__ float rd[256];
    __shared__ int   rk[256];
    int n = *flag_cnt;
    if (n > FLAG_CAP) n = FLAG_CAP;
    for (int idx = blockIdx.x; idx < n; idx += gridDim.x) {
        int tok = flag_list[idx];
        int d = tok >> 14;               // tok = d*NTOK + t
        int t = tok & (NTOK - 1);
        __syncthreads();
        if (threadIdx.x < ED) xs[threadIdx.x] = in[(size_t)t * HID + d * ED + threadIdx.x];
        __syncthreads();
        float x2v = 0.f;                 // strict serial, matches ref
        for (int e = 0; e < ED; ++e) x2v = __fadd_rn(x2v, __fmul_rn(xs[e], xs[e]));
        const float* __restrict__ embd = emb + (size_t)d * ED * KCODES;
        float bd = 3.0e38f; int bk = 0;
        for (int j = 0; j < 16; ++j) {
            int k = threadIdx.x + j * 256;      // ascending k per thread
            float acc = 0.f;
            #pragma unroll 16
            for (int e = 0; e < ED; ++e)
                acc = __fmaf_rn(xs[e], embd[(size_t)e * KCODES + k], acc);
            float dist = __fsub_rn(__fadd_rn(x2v, e2g[d * KCODES + k]),
                                   __fmul_rn(2.0f, acc));
            if (dist < bd) { bd = dist; bk = k; }
        }
        rd[threadIdx.x] = bd; rk[threadIdx.x] = bk;
        __syncthreads();
        for (int w = 128; w > 0; w >>= 1) {
            if (threadIdx.x < w) {
                float od = rd[threadIdx.x + w]; int ok = rk[threadIdx.x + w];
                if (od < rd[threadIdx.x] || (od == rd[threadIdx.x] && ok < rk[threadIdx.x])) {
                    rd[threadIdx.x] = od; rk[threadIdx.x] = ok;
                }
            }
            __syncthreads();
        }
        if (threadIdx.x == 0) lat[tok] = rk[0];
    }
}

// out[n] = fl(fl(x + e) - x), n = (d,e,t); per-block partials of (x - e)^2
__global__ __launch_bounds__(256) void gather_kernel(const float* __restrict__ in,
        const float* __restrict__ emb, const int* __restrict__ lat,
        float* __restrict__ out, float* __restrict__ partial) {
    int tid  = threadIdx.x;
    int base = blockIdx.x * 1024 + tid * 4;
    int d = base >> 21;
    int e = (base >> 14) & 127;
    int t = base & (NTOK - 1);
    const int4 kk = *(const int4*)(lat + d * NTOK + t);
    const float* __restrict__ row = emb + ((size_t)(d * ED + e)) * KCODES;
    float enc[4];
    enc[0] = row[kk.x]; enc[1] = row[kk.y]; enc[2] = row[kk.z]; enc[3] = row[kk.w];
    const float4 x = *(const float4*)(in + base);
    const float xv[4] = {x.x, x.y, x.z, x.w};
    float4 ov; float* o = (float*)&ov;
    float s = 0.f;
    #pragma unroll
    for (int i = 0; i < 4; ++i) {
        o[i] = __fsub_rn(__fadd_rn(xv[i], enc[i]), xv[i]);
        float df = xv[i] - enc[i];
        s = __fmaf_rn(df, df, s);
    }
    *(float4*)(out + base) = ov;
    #pragma unroll
    for (int off = 32; off > 0; off >>= 1) s += __shfl_down(s, off, 64);
    __shared__ float wsum[4];
    if ((tid & 63) == 0) wsum[tid >> 6] = s;
    __syncthreads();
    if (tid == 0) partial[blockIdx.x] = wsum[0] + wsum[1] + wsum[2] + wsum[3];
}

__global__ __launch_bounds__(256) void finalize_kernel(const float* __restrict__ partial,
                                                       float* __restrict__ out_tail) {
    __shared__ double sh[256];
    double s = 0.0;
    for (int i = threadIdx.x; i < 8192; i += 256) s += (double)partial[i];
    sh[threadIdx.x] = s;
    __syncthreads();
    for (int w = 128; w > 0; w >>= 1) {
        if (threadIdx.x < w) sh[threadIdx.x] += sh[threadIdx.x + w];
        __syncthreads();
    }
    if (threadIdx.x == 0) {
        double mean = sh[0] / (double)NTOT;
        out_tail[0] = (float)(0.25 * mean);   // loss
        out_tail[1] = (float)mean;            // commit_loss
        ((int*)out_tail)[2] = 0;              // kl (int32 0 == fp32 0.0 bits)
    }
}

extern "C" void kernel_launch(void* const* d_in, const int* in_sizes, int n_in,
                              void* d_out, int out_size, void* d_ws, size_t ws_size,
                              hipStream_t stream) {
    const float* in  = (const float*)d_in[0];
    const float* emb = (const float*)d_in[1];
    float* out = (float*)d_out;
    char* ws = (char*)d_ws;

    int*   lat       = (int*)ws;                         // 256 KB
    float* e2g       = (float*)(ws + 262144);            // 64 KB
    float* e2p       = (float*)(ws + 327680);            // 64 KB
    float* partial   = (float*)(ws + 393216);            // 32 KB
    int*   flag_cnt  = (int*)(ws + 425984);              // 4 B
    int*   flag_list = (int*)(ws + 425988);              // 64 KB
    unsigned short* bth2 = (unsigned short*)(ws + (1 << 20));             // 4 MB
    unsigned short* btl2 = (unsigned short*)(ws + (1 << 20) + 4194304);   // 4 MB

    hipLaunchKernelGGL(zero_kernel, dim3(1), dim3(64), 0, stream, flag_cnt);
    hipLaunchKernelGGL(e2_kernel, dim3(64), dim3(256), 0, stream, emb, e2g, e2p);
    hipLaunchKernelGGL(bsplit_kernel, dim3(64, 4), dim3(256), 0, stream, emb, bth2, btl2);
    hipLaunchKernelGGL(argmin_mfma_kernel, dim3(512), dim3(256), 0, stream,
                       in, bth2, btl2, e2p, lat, flag_cnt, flag_list);
    hipLaunchKernelGGL(repair_kernel, dim3(64), dim3(256), 0, stream,
                       in, emb, e2g, flag_cnt, flag_list, lat);
    hipLaunchKernelGGL(gather_kernel, dim3(NTOT / 1024), dim3(256), 0, stream,
                       in, emb, lat, out, partial);
    hipLaunchKernelGGL(finalize_kernel, dim3(1), dim3(256), 0, stream, partial, out + NTOT);
}